// Round 6
// baseline (43.933 us; speedup 1.0000x reference)
//
#include <hip/hip_runtime.h>
#include <math.h>

#define FDIM  50
#define EDIM  16
#define ADIM  16
#define NPAIR 1225
#define BROWS 16        // batch rows per block (MFMA cols)
#define NTHREADS 1024
#define NWAVE 16
#define CHUNK 77        // ceil(NPAIR / NWAVE) contiguous pairs per wave
#define FBLK  512       // bytes per f-block in LDS: [chunk4][b16][8B]

typedef _Float16 half4  __attribute__((ext_vector_type(4)));
typedef _Float16 half2v __attribute__((ext_vector_type(2)));
typedef __fp16   h16x4  __attribute__((ext_vector_type(4)));
typedef __fp16   h16x2  __attribute__((ext_vector_type(2)));
typedef float    f32x4  __attribute__((ext_vector_type(4)));

__device__ inline f32x4 mfma16x16x16f16(half4 a, half4 b, f32x4 c) {
    return __builtin_amdgcn_mfma_f32_16x16x16f16(
        __builtin_bit_cast(h16x4, a), __builtin_bit_cast(h16x4, b), c, 0, 0, 0);
}

__global__ __launch_bounds__(NTHREADS) void afm_fwd(
    const int*   __restrict__ feat_index,
    const float* __restrict__ feat_value,
    const float* __restrict__ emb_table,
    const float* __restrict__ attn_w,
    const float* __restrict__ attn_b,
    const float* __restrict__ attn_h,
    const float* __restrict__ attn_p,
    const float* __restrict__ lin_w,
    const float* __restrict__ lin_b,
    float*       __restrict__ out)
{
    __shared__ __align__(16) _Float16 embLds[FDIM * 256]; // [f][c][b][4] = 25.6 KB
    __shared__ float    redLds[NWAVE][BROWS][2];
    __shared__ float    ylinLds[BROWS];
    __shared__ float    lwLds[FDIM];

    const int t    = threadIdx.x;
    const int lane = t & 63;
    const int wv   = t >> 6;
    const int g    = lane >> 4;
    const int col  = lane & 15;
    const int b0   = blockIdx.x * BROWS;

    if (t < FDIM) lwLds[t] = lin_w[t];

    // ---- stage emb: t -> (f = t>>4, b = t&15); layout [f][chunk][b][4] ----
    {
        int bb = t & 15;
        int f  = t >> 4;               // 0..63 (f<50 active)
        if (f < FDIM) {
            int   fi = feat_index[(b0 + bb) * FDIM + f];
            float fv = feat_value[(b0 + bb) * FDIM + f];
            const float4* tr = (const float4*)(emb_table + (size_t)fi * EDIM);
            #pragma unroll
            for (int c = 0; c < 4; ++c) {
                float4 tv = tr[c];
                half4 h;
                h[0] = (_Float16)(tv.x * fv);
                h[1] = (_Float16)(tv.y * fv);
                h[2] = (_Float16)(tv.z * fv);
                h[3] = (_Float16)(tv.w * fv);
                *(half4*)&embLds[f*256 + c*64 + bb*4] = h;
            }
        }
    }
    __syncthreads();

    // ---- y_lin: threads 0..255: b = t>>4, e = t&15 ----
    if (t < 256) {
        int bb = t >> 4, e = t & 15;
        int off = (e >> 2) * 64 + bb * 4 + (e & 3);
        float acc = lin_b[0];
        #pragma unroll
        for (int f = 0; f < FDIM; ++f)
            acc = fmaf((float)embLds[f*256 + off], lwLds[f], acc);
        acc = fmaxf(acc, 0.0f);
        acc += __shfl_xor(acc, 1);
        acc += __shfl_xor(acc, 2);
        acc += __shfl_xor(acc, 4);
        acc += __shfl_xor(acc, 8);
        if (e == 0) ylinLds[bb] = acc;
    }

    // ---- loop-invariant fragments ----
    // MFMA1: D1[a][b] = sum_e W^T[a][e] * ewp[e][b] + bias[a]
    //   A1: lane holds row a=col, k=e=g*4+m  -> W[e][a]
    // MFMA2: D2[r][b] = sum_a (h[a]*log2e) * relu1[a][b]  -> exp2 at the end
    half4 fragA1, fragA2, ph;
    #pragma unroll
    for (int m = 0; m < 4; ++m) {
        int k = g * 4 + m;
        fragA1[m] = (_Float16)attn_w[k * ADIM + col];
        fragA2[m] = (_Float16)(attn_h[k] * 1.44269504f);
        ph[m]     = (_Float16)attn_p[k];
    }
    f32x4 biasC;
    #pragma unroll
    for (int m = 0; m < 4; ++m) biasC[m] = attn_b[g * 4 + m];
    const f32x4 zeroC = {0.f, 0.f, 0.f, 0.f};

    // ---- contiguous pair chunk for this wave: analytic (i,j) walk ----
    const int pbeg = wv * CHUNK;
    const int pend = (pbeg + CHUNK < NPAIR) ? pbeg + CHUNK : NPAIR;

    // decode (i,j) at pbeg (wave-uniform)
    float tq = 9801.0f - 8.0f * (float)pbeg;
    int i = (int)((99.0f - sqrtf(tq)) * 0.5f);
    i = max(0, min(48, i));
    while (i < 48 && (49*(i+1) - (((i+1)*i)>>1)) <= pbeg) ++i;
    while (i > 0  && (49*i - ((i*(i-1))>>1)) > pbeg) --i;
    int j = i + 1 + (pbeg - (49*i - ((i*(i-1))>>1)));

    const char* ebase = (const char*)embLds;
    const unsigned laddr = (unsigned)lane * 8u;
    unsigned vaj = (unsigned)(j * FBLK) + laddr;
    half4 ei = *(const half4*)(ebase + (unsigned)(i * FBLK) + laddr);

    float num = 0.f, den = 0.f;

    #pragma unroll 2
    for (int p = pbeg; p < pend; ++p) {
        half4 ej = *(const half4*)(ebase + vaj);
        half4 prod = ei * ej;                        // B1 fragment (k=g*4+m, col=b)

        half2v plo = __builtin_shufflevector(prod, prod, 0, 1);
        half2v phi = __builtin_shufflevector(prod, prod, 2, 3);
        half2v qlo = __builtin_shufflevector(ph, ph, 0, 1);
        half2v qhi = __builtin_shufflevector(ph, ph, 2, 3);
#if __has_builtin(__builtin_amdgcn_fdot2)
        float ud = __builtin_amdgcn_fdot2(
                      __builtin_bit_cast(h16x2, plo), __builtin_bit_cast(h16x2, qlo),
                      __builtin_amdgcn_fdot2(
                          __builtin_bit_cast(h16x2, phi), __builtin_bit_cast(h16x2, qhi),
                          0.f, false),
                      false);
#else
        half2v q2 = plo * qlo + phi * qhi;
        float ud = (float)q2[0] + (float)q2[1];
#endif
        f32x4 acc1 = mfma16x16x16f16(fragA1, prod, biasC);
        h16x2 rlo = __builtin_amdgcn_cvt_pkrtz(fmaxf(acc1[0], 0.f), fmaxf(acc1[1], 0.f));
        h16x2 rhi = __builtin_amdgcn_cvt_pkrtz(fmaxf(acc1[2], 0.f), fmaxf(acc1[3], 0.f));
        half4 rfrag = __builtin_bit_cast(half4,
                        __builtin_shufflevector(rlo, rhi, 0, 1, 2, 3)); // B2 frag == C1 layout
        f32x4 acc2 = mfma16x16x16f16(fragA2, rfrag, zeroC);
        float sc = exp2f(acc2[0]);                   // s[b] identical on all 4 g-groups
        num = fmaf(sc, ud, num);                     // ud covers this lane's 4 e's
        den += sc;                                   // counted 4x -> fixed at readout

        // advance (wave-uniform control)
        if (++j >= FDIM) {
            ++i; j = i + 1;
            ei  = *(const half4*)(ebase + (unsigned)(i * FBLK) + laddr);
            vaj = (unsigned)(j * FBLK) + laddr;
        } else {
            vaj += FBLK;
        }
    }

    // reduce the 4 g-groups (e-chunks) per b within the wave
    num += __shfl_xor(num, 16); num += __shfl_xor(num, 32);
    den += __shfl_xor(den, 16); den += __shfl_xor(den, 32);
    if (g == 0) { redLds[wv][col][0] = num; redLds[wv][col][1] = den; }
    __syncthreads();

    if (t < BROWS) {
        float nn = 0.f, dd = 0.f;
        #pragma unroll
        for (int w = 0; w < NWAVE; ++w) { nn += redLds[w][t][0]; dd += redLds[w][t][1]; }
        out[b0 + t] = 4.0f * nn / dd + ylinLds[t];   // den was counted 4x per pair
    }
}

extern "C" void kernel_launch(void* const* d_in, const int* in_sizes, int n_in,
                              void* d_out, int out_size, void* d_ws, size_t ws_size,
                              hipStream_t stream) {
    const int*   feat_index = (const int*)  d_in[0];
    const float* feat_value = (const float*)d_in[1];
    const float* emb_table  = (const float*)d_in[2];
    const float* attn_w     = (const float*)d_in[3];
    const float* attn_b     = (const float*)d_in[4];
    const float* attn_h     = (const float*)d_in[5];
    const float* attn_p     = (const float*)d_in[6];
    const float* lin_w      = (const float*)d_in[7];
    const float* lin_b      = (const float*)d_in[8];
    float* outp = (float*)d_out;

    dim3 grid(out_size / BROWS);   // 512 blocks of 16 batch rows
    dim3 block(NTHREADS);
    afm_fwd<<<grid, block, 0, stream>>>(feat_index, feat_value, emb_table,
                                        attn_w, attn_b, attn_h, attn_p,
                                        lin_w, lin_b, outp);
}

// Round 7
// 37.433 us; speedup vs baseline: 1.1736x; 1.1736x over previous
//
#include <hip/hip_runtime.h>
#include <math.h>

#define FDIM  50
#define EDIM  16
#define ADIM  16
#define NPAIR 1225
#define BROWS 32        // batch rows per block (MFMA cols)
#define NTHREADS 1024
#define NWAVE 16
#define FBLK  1024      // bytes per f-block in LDS: [lane64][16B]

typedef _Float16 half8v __attribute__((ext_vector_type(8)));
typedef __fp16   h16x8  __attribute__((ext_vector_type(8)));
typedef float    f32x16 __attribute__((ext_vector_type(16)));

__device__ inline f32x16 mfma32x32x16f16(half8v a, half8v b, f32x16 c) {
    return __builtin_amdgcn_mfma_f32_32x32x16_f16(
        __builtin_bit_cast(h16x8, a), __builtin_bit_cast(h16x8, b), c, 0, 0, 0);
}

__global__ __launch_bounds__(NTHREADS) void afm_fwd(
    const int*   __restrict__ feat_index,
    const float* __restrict__ feat_value,
    const float* __restrict__ emb_table,
    const float* __restrict__ attn_w,
    const float* __restrict__ attn_b,
    const float* __restrict__ attn_h,
    const float* __restrict__ attn_p,
    const float* __restrict__ lin_w,
    const float* __restrict__ lin_b,
    float*       __restrict__ out)
{
    // [f][lane64][8 f16]: lane = kh*32 + b, holds e = kh*8 .. kh*8+7 for batch col b
    __shared__ __align__(16) _Float16 embLds[FDIM * 512];   // 51200 B
    __shared__ unsigned ijLds[NPAIR];                       // (i*FBLK)<<16 | j*FBLK
    __shared__ float    redLds[NWAVE][BROWS][2];            // [wv][b][{num,den}]
    __shared__ float    ylinLds[BROWS];
    __shared__ float    lwLds[FDIM];

    const int t    = threadIdx.x;
    const int lane = t & 63;
    const int wv   = t >> 6;
    const int hi   = lane >> 5;    // k-half (and num/den role)
    const int col  = lane & 31;    // batch col (B) / D-row index for A
    const int b0   = blockIdx.x * BROWS;

    if (t < FDIM) lwLds[t] = lin_w[t];

    // ---- ij offset table ----
    for (int p = t; p < NPAIR; p += NTHREADS) {
        float tq = 9801.0f - 8.0f * (float)p;
        int ii = (int)((99.0f - sqrtf(tq)) * 0.5f);
        ii = max(0, min(48, ii));
        while (ii < 48 && (49*(ii+1) - (((ii+1)*ii)>>1)) <= p) ++ii;
        while (ii > 0  && (49*ii - ((ii*(ii-1))>>1)) > p) --ii;
        int q  = 49*ii - ((ii*(ii-1))>>1);
        int jj = ii + 1 + (p - q);
        ijLds[p] = ((unsigned)(ii*FBLK) << 16) | (unsigned)(jj*FBLK);
    }

    // ---- stage emb: lane l -> (b=l&31, kh=l>>5); f = (t>>6)+16*pass ----
    for (int f = t >> 6; f < FDIM; f += NWAVE) {
        int   fi = feat_index[(b0 + col) * FDIM + f];
        float fv = feat_value[(b0 + col) * FDIM + f];
        const float4* tr = (const float4*)(emb_table + (size_t)fi * EDIM + hi * 8);
        float4 v0 = tr[0], v1 = tr[1];
        half8v h;
        h[0] = (_Float16)(v0.x * fv); h[1] = (_Float16)(v0.y * fv);
        h[2] = (_Float16)(v0.z * fv); h[3] = (_Float16)(v0.w * fv);
        h[4] = (_Float16)(v1.x * fv); h[5] = (_Float16)(v1.y * fv);
        h[6] = (_Float16)(v1.z * fv); h[7] = (_Float16)(v1.w * fv);
        *(half8v*)&embLds[f * 512 + lane * 8] = h;
    }
    __syncthreads();

    // ---- y_lin: threads 0..511: b = t>>4, e = t&15 ----
    if (t < 512) {
        int bb = t >> 4, e = t & 15;
        int off = (e >> 3) * 256 + bb * 8 + (e & 7);
        float acc = lin_b[0];
        #pragma unroll
        for (int f = 0; f < FDIM; ++f)
            acc = fmaf((float)embLds[f * 512 + off], lwLds[f], acc);
        acc = fmaxf(acc, 0.0f);
        acc += __shfl_xor(acc, 1);
        acc += __shfl_xor(acc, 2);
        acc += __shfl_xor(acc, 4);
        acc += __shfl_xor(acc, 8);
        if (e == 0) ylinLds[bb] = acc;
    }

    // ---- loop-invariant fragments ----
    // MFMA: D[m][b] = sum_e A[m][e] * ewp[e][b] (+C).  A rows: m<16 -> W^T, m==16 -> p, else 0.
    // A lane map: m = col, k = hi*8 + e.  B lane map: b = col, k = hi*8 + e.
    half8v fragA1;
    #pragma unroll
    for (int e = 0; e < 8; ++e) {
        int k = hi * 8 + e;
        float av = (col < ADIM) ? attn_w[k * ADIM + col]
                 : (col == ADIM) ? attn_p[k] : 0.0f;
        fragA1[e] = (_Float16)av;
    }
    // C/D row map (verified): r = (reg&3) + 8*(reg>>2) + 4*hi, regs 0..7 -> a rows 0..15
    float hrow[8], brow[8];
    #pragma unroll
    for (int reg = 0; reg < 8; ++reg) {
        int r = (reg & 3) + 8 * (reg >> 2) + 4 * hi;
        hrow[reg] = attn_h[r] * 1.44269504f;   // fold log2(e) -> exp2 at the end
        brow[reg] = attn_b[r];
    }
    f32x16 biasC;
    #pragma unroll
    for (int reg = 0; reg < 8; ++reg) { biasC[reg] = brow[reg]; biasC[reg + 8] = 0.f; }

    const char* ebase = (const char*)embLds;
    const unsigned laddr = (unsigned)lane * 16u;
    float num = 0.f, den = 0.f;

    #pragma unroll 2
    for (int p = wv; p < NPAIR; p += NWAVE) {
        unsigned u = ijLds[p];                         // wave-uniform broadcast
        half8v ei = *(const half8v*)(ebase + (u >> 16)      + laddr);
        half8v ej = *(const half8v*)(ebase + (u & 0xffffu)  + laddr);
        half8v prod = ei * ej;                         // B fragment (k=hi*8+e, col=b)

        f32x16 acc1 = mfma32x32x16f16(fragA1, prod, biasC);

        float s = 0.f;
        #pragma unroll
        for (int reg = 0; reg < 8; ++reg)
            s = fmaf(fmaxf(acc1[reg], 0.f), hrow[reg], s);
        s += __shfl_xor(s, 32);                        // combine the two 8-row halves
        float sc = exp2f(s);
        if (hi) den += sc;                             // lanes>=32: denominator
        else    num = fmaf(sc, acc1[8], num);          // lanes<32: acc1[8] = u (row 16)
    }

    if (hi) redLds[wv][col][1] = den;
    else    redLds[wv][col][0] = num;
    __syncthreads();

    if (t < BROWS) {
        float nn = 0.f, dd = 0.f;
        #pragma unroll
        for (int w = 0; w < NWAVE; ++w) { nn += redLds[w][t][0]; dd += redLds[w][t][1]; }
        out[b0 + t] = nn / dd + ylinLds[t];
    }
}

extern "C" void kernel_launch(void* const* d_in, const int* in_sizes, int n_in,
                              void* d_out, int out_size, void* d_ws, size_t ws_size,
                              hipStream_t stream) {
    const int*   feat_index = (const int*)  d_in[0];
    const float* feat_value = (const float*)d_in[1];
    const float* emb_table  = (const float*)d_in[2];
    const float* attn_w     = (const float*)d_in[3];
    const float* attn_b     = (const float*)d_in[4];
    const float* attn_h     = (const float*)d_in[5];
    const float* attn_p     = (const float*)d_in[6];
    const float* lin_w      = (const float*)d_in[7];
    const float* lin_b      = (const float*)d_in[8];
    float* outp = (float*)d_out;

    dim3 grid(out_size / BROWS);   // 256 blocks of 32 batch rows
    dim3 block(NTHREADS);
    afm_fwd<<<grid, block, 0, stream>>>(feat_index, feat_value, emb_table,
                                        attn_w, attn_b, attn_h, attn_p,
                                        lin_w, lin_b, outp);
}

// Round 8
// 35.323 us; speedup vs baseline: 1.2438x; 1.0597x over previous
//
#include <hip/hip_runtime.h>
#include <math.h>

#define FDIM  50
#define EDIM  16
#define ADIM  16
#define NPAIR 1225
#define BROWS 32        // batch rows per block (MFMA cols)
#define NTHREADS 1024
#define NWAVE 16
#define NPAD  (NPAIR + 2 * NWAVE)   // padded ij table for prefetch overread
#define FBLK  1024      // bytes per f-block in LDS: [lane64][16B]

typedef _Float16 half8v __attribute__((ext_vector_type(8)));
typedef __fp16   h16x8  __attribute__((ext_vector_type(8)));
typedef float    f32x16 __attribute__((ext_vector_type(16)));

__device__ inline f32x16 mfma32x32x16f16(half8v a, half8v b, f32x16 c) {
    return __builtin_amdgcn_mfma_f32_32x32x16_f16(
        __builtin_bit_cast(h16x8, a), __builtin_bit_cast(h16x8, b), c, 0, 0, 0);
}

__global__ __launch_bounds__(NTHREADS) void afm_fwd(
    const int*   __restrict__ feat_index,
    const float* __restrict__ feat_value,
    const float* __restrict__ emb_table,
    const float* __restrict__ attn_w,
    const float* __restrict__ attn_b,
    const float* __restrict__ attn_h,
    const float* __restrict__ attn_p,
    const float* __restrict__ lin_w,
    const float* __restrict__ lin_b,
    float*       __restrict__ out)
{
    // [f][lane64][8 f16]: lane = kh*32 + b, holds e = kh*8 .. kh*8+7 for batch col b
    __shared__ __align__(16) _Float16 embLds[FDIM * 512];   // 51200 B
    __shared__ unsigned ijLds[NPAD];                        // (i*FBLK)<<16 | j*FBLK
    __shared__ float    redLds[NWAVE][BROWS][2];            // [wv][b][{num,den}]
    __shared__ float    ylinLds[BROWS];
    __shared__ float    lwLds[FDIM];

    const int t    = threadIdx.x;
    const int lane = t & 63;
    const int wv   = t >> 6;
    const int hi   = lane >> 5;    // k-half (and num/den role)
    const int col  = lane & 31;    // batch col (B) / D-row index for A
    const int b0   = blockIdx.x * BROWS;

    if (t < FDIM) lwLds[t] = lin_w[t];

    // ---- ij offset table (padded; tail repeats last pair for safe prefetch) ----
    for (int p = t; p < NPAD; p += NTHREADS) {
        int pc = (p < NPAIR) ? p : NPAIR - 1;
        float tq = 9801.0f - 8.0f * (float)pc;
        int ii = (int)((99.0f - sqrtf(tq)) * 0.5f);
        ii = max(0, min(48, ii));
        while (ii < 48 && (49*(ii+1) - (((ii+1)*ii)>>1)) <= pc) ++ii;
        while (ii > 0  && (49*ii - ((ii*(ii-1))>>1)) > pc) --ii;
        int q  = 49*ii - ((ii*(ii-1))>>1);
        int jj = ii + 1 + (pc - q);
        ijLds[p] = ((unsigned)(ii*FBLK) << 16) | (unsigned)(jj*FBLK);
    }

    // ---- stage emb: lane l -> (b=l&31, kh=l>>5); f = (t>>6)+16*pass ----
    for (int f = t >> 6; f < FDIM; f += NWAVE) {
        int   fi = feat_index[(b0 + col) * FDIM + f];
        float fv = feat_value[(b0 + col) * FDIM + f];
        const float4* tr = (const float4*)(emb_table + (size_t)fi * EDIM + hi * 8);
        float4 v0 = tr[0], v1 = tr[1];
        half8v h;
        h[0] = (_Float16)(v0.x * fv); h[1] = (_Float16)(v0.y * fv);
        h[2] = (_Float16)(v0.z * fv); h[3] = (_Float16)(v0.w * fv);
        h[4] = (_Float16)(v1.x * fv); h[5] = (_Float16)(v1.y * fv);
        h[6] = (_Float16)(v1.z * fv); h[7] = (_Float16)(v1.w * fv);
        *(half8v*)&embLds[f * 512 + lane * 8] = h;
    }
    __syncthreads();

    // ---- y_lin: threads 0..511: b = t>>4, e = t&15 ----
    if (t < 512) {
        int bb = t >> 4, e = t & 15;
        int off = (e >> 3) * 256 + bb * 8 + (e & 7);
        float acc = lin_b[0];
        #pragma unroll
        for (int f = 0; f < FDIM; ++f)
            acc = fmaf((float)embLds[f * 512 + off], lwLds[f], acc);
        acc = fmaxf(acc, 0.0f);
        acc += __shfl_xor(acc, 1);
        acc += __shfl_xor(acc, 2);
        acc += __shfl_xor(acc, 4);
        acc += __shfl_xor(acc, 8);
        if (e == 0) ylinLds[bb] = acc;
    }

    // ---- loop-invariant fragments ----
    // MFMA: D[m][b] = sum_e A[m][e] * ewp[e][b] (+C).  A rows: m<16 -> W^T, m==16 -> p, else 0.
    // A lane map: m = col, k = hi*8 + e.  B lane map: b = col, k = hi*8 + e.
    half8v fragA1;
    #pragma unroll
    for (int e = 0; e < 8; ++e) {
        int k = hi * 8 + e;
        float av = (col < ADIM) ? attn_w[k * ADIM + col]
                 : (col == ADIM) ? attn_p[k] : 0.0f;
        fragA1[e] = (_Float16)av;
    }
    // C/D row map (verified): r = (reg&3) + 8*(reg>>2) + 4*hi, regs 0..7 -> a rows 0..15
    float hrow[8];
    f32x16 biasC;
    #pragma unroll
    for (int reg = 0; reg < 8; ++reg) {
        int r = (reg & 3) + 8 * (reg >> 2) + 4 * hi;
        hrow[reg]  = attn_h[r] * 1.44269504f;   // fold log2(e) -> exp2 at the end
        biasC[reg] = attn_b[r];
        biasC[reg + 8] = 0.f;
    }

    const char* ebase = (const char*)embLds;
    const unsigned laddr = (unsigned)lane * 16u;

    // ---- software-pipelined pair loop (1-deep prefetch) ----
    float num = 0.f, den = 0.f;
    unsigned u0   = ijLds[wv];
    half8v   ei   = *(const half8v*)(ebase + (u0 >> 16)     + laddr);
    half8v   ej   = *(const half8v*)(ebase + (u0 & 0xffffu) + laddr);
    unsigned unxt = ijLds[wv + NWAVE];

    #pragma unroll 2
    for (int p = wv; p < NPAIR; p += NWAVE) {
        // issue next iteration's loads first (overlaps with compute below)
        half8v ei_n = *(const half8v*)(ebase + (unxt >> 16)     + laddr);
        half8v ej_n = *(const half8v*)(ebase + (unxt & 0xffffu) + laddr);
        unsigned u2 = ijLds[p + 2 * NWAVE];

        half8v prod = ei * ej;                         // B fragment (k=hi*8+e, col=b)
        f32x16 acc1 = mfma32x32x16f16(fragA1, prod, biasC);

        float s0 = 0.f, s1 = 0.f;                      // two parallel 4-deep chains
        #pragma unroll
        for (int reg = 0; reg < 4; ++reg) {
            s0 = fmaf(fmaxf(acc1[reg],     0.f), hrow[reg],     s0);
            s1 = fmaf(fmaxf(acc1[reg + 4], 0.f), hrow[reg + 4], s1);
        }
        float s = s0 + s1;
        s += __shfl_xor(s, 32);                        // combine the two 8-row halves
        float sc = __builtin_amdgcn_exp2f(s);
        if (hi) den += sc;                             // lanes>=32: denominator
        else    num = fmaf(sc, acc1[8], num);          // lanes<32: acc1[8] = u (row 16)

        ei = ei_n; ej = ej_n; unxt = u2;
    }

    if (hi) redLds[wv][col][1] = den;
    else    redLds[wv][col][0] = num;
    __syncthreads();

    if (t < BROWS) {
        float nn = 0.f, dd = 0.f;
        #pragma unroll
        for (int w = 0; w < NWAVE; ++w) { nn += redLds[w][t][0]; dd += redLds[w][t][1]; }
        out[b0 + t] = nn / dd + ylinLds[t];
    }
}

extern "C" void kernel_launch(void* const* d_in, const int* in_sizes, int n_in,
                              void* d_out, int out_size, void* d_ws, size_t ws_size,
                              hipStream_t stream) {
    const int*   feat_index = (const int*)  d_in[0];
    const float* feat_value = (const float*)d_in[1];
    const float* emb_table  = (const float*)d_in[2];
    const float* attn_w     = (const float*)d_in[3];
    const float* attn_b     = (const float*)d_in[4];
    const float* attn_h     = (const float*)d_in[5];
    const float* attn_p     = (const float*)d_in[6];
    const float* lin_w      = (const float*)d_in[7];
    const float* lin_b      = (const float*)d_in[8];
    float* outp = (float*)d_out;

    dim3 grid(out_size / BROWS);   // 256 blocks of 32 batch rows
    dim3 block(NTHREADS);
    afm_fwd<<<grid, block, 0, stream>>>(feat_index, feat_value, emb_table,
                                        attn_w, attn_b, attn_h, attn_p,
                                        lin_w, lin_b, outp);
}